// Round 2
// baseline (1534.196 us; speedup 1.0000x reference)
//
#include <hip/hip_runtime.h>

#define EE     1600000
#define NDIM   64
#define EDIM   32
#define NLAYER 3
#define INDIM  160      // EDIM + 2*NDIM
#define TPB    256
#define EPT    2
#define EPB    (TPB*EPT)   // 512 edges per block

static_assert(EE % EPB == 0, "grid must divide evenly");

// One thread handles 2 edges; all 3 layers fused (node features are
// layer-invariant, each edge's chain is independent). LayerNorm folded:
//   h1 = rs * (x @ W1') + (-mu*rs) * C2 + C1b,  W1' = g (.) W1 (rows scaled),
//   C2[k] = sum_d W1'[d][k],  C1b[k] = ln_b @ W1 + b1[k].
// Weights staged per-layer in LDS (broadcast reads); x streamed from global
// (nodes are L2/L3-resident: 25.6 MB table).
__global__ __launch_bounds__(TPB, 2) void edge_mlp_fused(
  const float* __restrict__ nf,  const float* __restrict__ ew,
  const float* __restrict__ lng, const float* __restrict__ lnb,
  const float* __restrict__ w1,  const float* __restrict__ b1,
  const float* __restrict__ w2,  const float* __restrict__ b2,
  const int* __restrict__ ei, const int* __restrict__ ej,
  float* __restrict__ out)
{
  __shared__ float sW1[INDIM*EDIM];   // 20 KB: W1'[d][k] = g_d * W1[d][k]
  __shared__ float sW2[EDIM*EDIM];    // 4 KB
  __shared__ float sC2[EDIM], sC1b[EDIM], sB2[EDIM];

  const int tid = threadIdx.x;
  const int id0 = blockIdx.x * EPB + tid;
  const int id1 = id0 + TPB;

  const float4* pi0 = (const float4*)(nf + (size_t)ei[id0] * NDIM);
  const float4* pj0 = (const float4*)(nf + (size_t)ej[id0] * NDIM);
  const float4* pi1 = (const float4*)(nf + (size_t)ei[id1] * NDIM);
  const float4* pj1 = (const float4*)(nf + (size_t)ej[id1] * NDIM);

  float e0[EDIM], e1[EDIM];
  {
    const float4* a = (const float4*)(ew + (size_t)id0 * EDIM);
    const float4* b = (const float4*)(ew + (size_t)id1 * EDIM);
    #pragma unroll
    for (int c = 0; c < 8; ++c){
      float4 v = a[c];
      e0[4*c+0]=v.x; e0[4*c+1]=v.y; e0[4*c+2]=v.z; e0[4*c+3]=v.w;
      float4 u = b[c];
      e1[4*c+0]=u.x; e1[4*c+1]=u.y; e1[4*c+2]=u.z; e1[4*c+3]=u.w;
    }
  }

  #pragma unroll 1
  for (int l = 0; l < NLAYER; ++l){
    __syncthreads();  // prior layer's LDS readers done before rewrite
    const float* w1l = w1 + (size_t)l * INDIM * EDIM;

    // ---- stage W1' = g (.) W1 : 1280 float4 chunks, 5 per thread ----
    #pragma unroll
    for (int it = 0; it < 5; ++it){
      const int c = tid + it * TPB;
      const int d = c >> 3, ks = (c & 7) * 4;
      float4 v = *(const float4*)(w1l + d * EDIM + ks);
      const float g = lng[l * INDIM + d];
      sW1[d*EDIM+ks+0] = g*v.x; sW1[d*EDIM+ks+1] = g*v.y;
      sW1[d*EDIM+ks+2] = g*v.z; sW1[d*EDIM+ks+3] = g*v.w;
    }
    { // W2: 256 float4 chunks, one per thread
      const int d = tid >> 3, ks = (tid & 7) * 4;
      float4 v = *(const float4*)(w2 + (size_t)l*EDIM*EDIM + d*EDIM + ks);
      sW2[d*EDIM+ks+0] = v.x; sW2[d*EDIM+ks+1] = v.y;
      sW2[d*EDIM+ks+2] = v.z; sW2[d*EDIM+ks+3] = v.w;
    }
    if (tid < EDIM){
      float c1 = b1[l*EDIM + tid];
      for (int d = 0; d < INDIM; ++d)
        c1 = fmaf(lnb[l*INDIM + d], w1l[d*EDIM + tid], c1);
      sC1b[tid] = c1;
      sB2[tid]  = b2[l*EDIM + tid];
    }
    __syncthreads();
    if (tid < EDIM){
      float s = 0.f;
      for (int d = 0; d < INDIM; ++d) s += sW1[d*EDIM + tid];
      sC2[tid] = s;
    }
    __syncthreads();

    // ---- S = x @ W1' + LN stats, both edges ----
    float S0[EDIM], S1[EDIM];
    #pragma unroll
    for (int k = 0; k < EDIM; ++k){ S0[k] = 0.f; S1[k] = 0.f; }
    float sum0 = 0.f, sq0 = 0.f, sum1 = 0.f, sq1 = 0.f;

    auto dot_row = [&](float xv0, float xv1, const float4* row){
      sum0 += xv0; sq0 = fmaf(xv0, xv0, sq0);
      sum1 += xv1; sq1 = fmaf(xv1, xv1, sq1);
      #pragma unroll
      for (int q = 0; q < 8; ++q){
        float4 w = row[q];
        S0[4*q+0] = fmaf(xv0, w.x, S0[4*q+0]); S1[4*q+0] = fmaf(xv1, w.x, S1[4*q+0]);
        S0[4*q+1] = fmaf(xv0, w.y, S0[4*q+1]); S1[4*q+1] = fmaf(xv1, w.y, S1[4*q+1]);
        S0[4*q+2] = fmaf(xv0, w.z, S0[4*q+2]); S1[4*q+2] = fmaf(xv1, w.z, S1[4*q+2]);
        S0[4*q+3] = fmaf(xv0, w.w, S0[4*q+3]); S1[4*q+3] = fmaf(xv1, w.w, S1[4*q+3]);
      }
    };

    #pragma unroll 1
    for (int c = 0; c < 32; ++c){          // 32 float4 chunks = nf_i | nf_j
      const float4 x0 = (c < 16) ? pi0[c] : pj0[c - 16];
      const float4 x1 = (c < 16) ? pi1[c] : pj1[c - 16];
      const float4* wr = (const float4*)&sW1[c * 4 * EDIM];
      dot_row(x0.x, x1.x, wr + 0);
      dot_row(x0.y, x1.y, wr + 8);
      dot_row(x0.z, x1.z, wr + 16);
      dot_row(x0.w, x1.w, wr + 24);
    }
    #pragma unroll
    for (int d = 0; d < EDIM; ++d){        // e-section (registers)
      const float4* row = (const float4*)&sW1[(2*NDIM + d) * EDIM];
      dot_row(e0[d], e1[d], row);
    }

    const float mu0 = sum0 * (1.f/INDIM);
    const float va0 = fmaxf(fmaf(-mu0, mu0, sq0 * (1.f/INDIM)), 0.f);
    const float rs0 = rsqrtf(va0 + 1e-5f);
    const float nm0 = -mu0 * rs0;
    const float mu1 = sum1 * (1.f/INDIM);
    const float va1 = fmaxf(fmaf(-mu1, mu1, sq1 * (1.f/INDIM)), 0.f);
    const float rs1 = rsqrtf(va1 + 1e-5f);
    const float nm1 = -mu1 * rs1;

    float h0[EDIM], h1v[EDIM];
    #pragma unroll
    for (int k = 0; k < EDIM; ++k){
      float a = fmaf(rs0, S0[k], fmaf(nm0, sC2[k], sC1b[k]));
      h0[k]  = fmaxf(a, 0.01f * a);        // LeakyReLU (slope < 1)
      float b = fmaf(rs1, S1[k], fmaf(nm1, sC2[k], sC1b[k]));
      h1v[k] = fmaxf(b, 0.01f * b);
    }
    #pragma unroll
    for (int k = 0; k < EDIM; ++k){ e0[k] += sB2[k]; e1[k] += sB2[k]; }
    #pragma unroll
    for (int d = 0; d < EDIM; ++d){        // second linear, accumulate into e
      const float a = h0[d], b = h1v[d];
      const float4* row = (const float4*)&sW2[d * EDIM];
      #pragma unroll
      for (int q = 0; q < 8; ++q){
        float4 w = row[q];
        e0[4*q+0] = fmaf(a, w.x, e0[4*q+0]); e1[4*q+0] = fmaf(b, w.x, e1[4*q+0]);
        e0[4*q+1] = fmaf(a, w.y, e0[4*q+1]); e1[4*q+1] = fmaf(b, w.y, e1[4*q+1]);
        e0[4*q+2] = fmaf(a, w.z, e0[4*q+2]); e1[4*q+2] = fmaf(b, w.z, e1[4*q+2]);
        e0[4*q+3] = fmaf(a, w.w, e0[4*q+3]); e1[4*q+3] = fmaf(b, w.w, e1[4*q+3]);
      }
    }
  }

  float4* o0 = (float4*)(out + (size_t)id0 * EDIM);
  float4* o1 = (float4*)(out + (size_t)id1 * EDIM);
  #pragma unroll
  for (int c = 0; c < 8; ++c){
    o0[c] = make_float4(e0[4*c+0], e0[4*c+1], e0[4*c+2], e0[4*c+3]);
    o1[c] = make_float4(e1[4*c+0], e1[4*c+1], e1[4*c+2], e1[4*c+3]);
  }
}

extern "C" void kernel_launch(void* const* d_in, const int* in_sizes, int n_in,
                              void* d_out, int out_size, void* d_ws, size_t ws_size,
                              hipStream_t stream)
{
  const float* nf  = (const float*)d_in[0];
  const float* ew  = (const float*)d_in[1];
  const float* lng = (const float*)d_in[2];
  const float* lnb = (const float*)d_in[3];
  const float* w1  = (const float*)d_in[4];
  const float* b1  = (const float*)d_in[5];
  const float* w2  = (const float*)d_in[6];
  const float* b2  = (const float*)d_in[7];
  const int*   ei  = (const int*)d_in[8];
  const int*   ej  = (const int*)d_in[9];
  float* out = (float*)d_out;

  dim3 grid(EE / EPB), block(TPB);
  hipLaunchKernelGGL(edge_mlp_fused, grid, block, 0, stream,
                     nf, ew, lng, lnb, w1, b1, w2, b2, ei, ej, out);
}